// Round 1
// baseline (4262.574 us; speedup 1.0000x reference)
//
#include <hip/hip_runtime.h>
#include <math.h>

// OctreeAttention: C=256, H=8, HD=32, K=32, G=8, W=40, NW=4096, RPE_NUM=51
#define SCALE_F 0.17677669529663687f  // 32^-0.5

// LDS carve (floats), total 29800 floats = 119200 B:
// s_data  [0,     10240)  [40][256] window tokens
// s_w     [10240, 18432)  8192: staged weight chunk (qkv: [64][96], proj: [32][256])
// s_q     [18432, 19712)  [40][32]  (reused as outh after PV)
// s_kT    [19712, 21024)  [32][41]  k transposed, padded
// s_v     [21024, 22304)  [40][32]
// s_attn  [22304, 23904)  [40][40]  (aliased as s_red[2][8][96] during std reduce)
// s_mask  [23904, 25504)  [40][40]
// s_idx   [25504, 28576)  3072 ints (clamped rpe row indices)
// s_rpe   [28576, 29800)  [153][8]

__global__ __launch_bounds__(256, 1)
void octa_main(const float* __restrict__ data, const int* __restrict__ rel_pos,
               const float* __restrict__ mask, const float* __restrict__ qkv_w,
               const float* __restrict__ qkv_b, const float* __restrict__ proj_w,
               const float* __restrict__ proj_b, const float* __restrict__ rpe_table,
               float* __restrict__ ws, float* __restrict__ out)
{
    extern __shared__ float sm[];
    float* s_data = sm;
    float* s_w    = sm + 10240;
    float* s_q    = sm + 18432;
    float* s_kT   = sm + 19712;
    float* s_v    = sm + 21024;
    float* s_attn = sm + 22304;
    float* s_mask = sm + 23904;
    int*   s_idx  = (int*)(sm + 25504);
    float* s_rpe  = sm + 28576;

    const int tid = threadIdx.x;
    const int w   = blockIdx.x;
    const int ct  = tid & 31;   // col within 32
    const int rg  = tid >> 5;   // row group (0..7), 5 rows each
    const int i0  = rg * 5;

    // ---------------- phase 0: stage per-window data ----------------
    {
        const float4* src = (const float4*)(data + (size_t)w * 10240);
        float4* dst = (float4*)s_data;
        #pragma unroll
        for (int rep = 0; rep < 10; ++rep) dst[tid + rep * 256] = src[tid + rep * 256];

        const float4* msrc = (const float4*)(mask + (size_t)w * 1600);
        float4* mdst = (float4*)s_mask;
        for (int f = tid; f < 400; f += 256) mdst[f] = msrc[f];

        const int4* isrc = (const int4*)(rel_pos + (size_t)w * 3072);
        for (int f = tid; f < 768; f += 256) {
            int4 v = isrc[f];
            int vv[4] = {v.x, v.y, v.z, v.w};
            #pragma unroll
            for (int c = 0; c < 4; ++c) {
                int flat = f * 4 + c;
                int axis = flat % 3;
                int cv = vv[c];
                cv = cv < -25 ? -25 : (cv > 25 ? 25 : cv);
                s_idx[flat] = cv + 25 + axis * 51;   // row of rpe_table (153 x 8)
            }
        }
        for (int f = tid; f < 1224; f += 256) s_rpe[f] = rpe_table[f];
    }

    // proj output accumulators: 5 rows x cols {ct + 32*m}
    float accO[5][8];
    #pragma unroll
    for (int r = 0; r < 5; ++r)
        #pragma unroll
        for (int m = 0; m < 8; ++m) accO[r][m] = 0.f;

    for (int h = 0; h < 8; ++h) {
        // -------- qkv GEMM for head h: (40x256)@(256x96) -> q,k,v 40x32 each --------
        float acc[5][3];
        #pragma unroll
        for (int r = 0; r < 5; ++r) { acc[r][0] = 0.f; acc[r][1] = 0.f; acc[r][2] = 0.f; }

        for (int kc = 0; kc < 4; ++kc) {
            __syncthreads();  // previous s_w readers done
            // stage s_w[64][96]: k rows kc*64.., cols = {q,k,v}[h*32 .. h*32+32)
            #pragma unroll
            for (int rep = 0; rep < 6; ++rep) {
                int f = tid + rep * 256;          // float4 units, 1536 total
                int kk = f / 24, rem = f % 24;
                int p = rem >> 3, j4 = (rem & 7) * 4;
                *(float4*)(s_w + kk * 96 + p * 32 + j4) =
                    *(const float4*)(qkv_w + (size_t)(kc * 64 + kk) * 768 + p * 256 + h * 32 + j4);
            }
            __syncthreads();
            const float* A = s_data + kc * 64;
            for (int kk = 0; kk < 64; kk += 4) {
                float wv[3][4];
                #pragma unroll
                for (int m = 0; m < 4; ++m) {
                    wv[0][m] = s_w[(kk + m) * 96 + ct];
                    wv[1][m] = s_w[(kk + m) * 96 + 32 + ct];
                    wv[2][m] = s_w[(kk + m) * 96 + 64 + ct];
                }
                #pragma unroll
                for (int r = 0; r < 5; ++r) {
                    float4 a = *(const float4*)(A + (i0 + r) * 256 + kk);
                    acc[r][0] += a.x * wv[0][0] + a.y * wv[0][1] + a.z * wv[0][2] + a.w * wv[0][3];
                    acc[r][1] += a.x * wv[1][0] + a.y * wv[1][1] + a.z * wv[1][2] + a.w * wv[1][3];
                    acc[r][2] += a.x * wv[2][0] + a.y * wv[2][1] + a.z * wv[2][2] + a.w * wv[2][3];
                }
            }
        }
        // bias + store q/kT/v + std partials
        {
            float bq = qkv_b[h * 32 + ct];
            float bk = qkv_b[256 + h * 32 + ct];
            float bv = qkv_b[512 + h * 32 + ct];
            float s1[3] = {0, 0, 0}, s2[3] = {0, 0, 0};
            #pragma unroll
            for (int r = 0; r < 5; ++r) {
                int i = i0 + r;
                float vq = acc[r][0] + bq;
                float vk = acc[r][1] + bk;
                float vv = acc[r][2] + bv;
                s_q[i * 32 + ct] = vq;
                s_kT[ct * 41 + i] = vk;
                s_v[i * 32 + ct] = vv;
                s1[0] += vq; s2[0] += vq * vq;
                s1[1] += vk; s2[1] += vk * vk;
                s1[2] += vv; s2[2] += vv * vv;
            }
            float* s_red = s_attn;  // alias: [2][8][96]
            #pragma unroll
            for (int p = 0; p < 3; ++p) {
                s_red[rg * 96 + p * 32 + ct] = s1[p];
                s_red[768 + rg * 96 + p * 32 + ct] = s2[p];
            }
        }
        __syncthreads();
        if (tid < 96) {
            float* s_red = s_attn;
            float t1 = 0.f, t2 = 0.f;
            #pragma unroll
            for (int g = 0; g < 8; ++g) { t1 += s_red[g * 96 + tid]; t2 += s_red[768 + g * 96 + tid]; }
            int col = (tid >> 5) * 256 + h * 32 + (tid & 31);
            atomicAdd(ws + col, t1);
            atomicAdd(ws + 768 + col, t2);
        }
        __syncthreads();  // s_red reads done before s_attn written

        // -------- attn logits: SCALE * q . k^T --------
        {
            float a5[5] = {0, 0, 0, 0, 0};
            for (int d = 0; d < 32; d += 4) {
                float b0 = s_kT[(d + 0) * 41 + ct];
                float b1 = s_kT[(d + 1) * 41 + ct];
                float b2 = s_kT[(d + 2) * 41 + ct];
                float b3 = s_kT[(d + 3) * 41 + ct];
                #pragma unroll
                for (int r = 0; r < 5; ++r) {
                    float4 a = *(const float4*)(s_q + (i0 + r) * 32 + d);
                    a5[r] += a.x * b0 + a.y * b1 + a.z * b2 + a.w * b3;
                }
            }
            #pragma unroll
            for (int r = 0; r < 5; ++r) s_attn[(i0 + r) * 40 + ct] = a5[r] * SCALE_F;
            // tail columns kj = 32..39
            for (int e = tid; e < 320; e += 256) {
                int qi = e >> 3, kj = 32 + (e & 7);
                float dsum = 0.f;
                for (int d = 0; d < 32; d += 4) {
                    float4 a = *(const float4*)(s_q + qi * 32 + d);
                    dsum += a.x * s_kT[(d + 0) * 41 + kj] + a.y * s_kT[(d + 1) * 41 + kj]
                          + a.z * s_kT[(d + 2) * 41 + kj] + a.w * s_kT[(d + 3) * 41 + kj];
                }
                s_attn[qi * 40 + kj] = dsum * SCALE_F;
            }
        }
        __syncthreads();

        // -------- + mask + RPE --------
        for (int e = tid; e < 1600; e += 256) {
            int qi = e / 40, kj = e - qi * 40;
            float val = s_attn[e] + s_mask[e];
            if (qi >= 8 && kj >= 8) {
                int b = ((qi - 8) * 32 + (kj - 8)) * 3;
                val += s_rpe[s_idx[b] * 8 + h] + s_rpe[s_idx[b + 1] * 8 + h]
                     + s_rpe[s_idx[b + 2] * 8 + h];
            }
            s_attn[e] = val;
        }
        __syncthreads();

        // -------- softmax per row --------
        if (tid < 40) {
            float* row = s_attn + tid * 40;
            float mx = row[0];
            for (int j2 = 1; j2 < 40; ++j2) mx = fmaxf(mx, row[j2]);
            float sum = 0.f;
            for (int j2 = 0; j2 < 40; ++j2) { float ex = __expf(row[j2] - mx); row[j2] = ex; sum += ex; }
            float inv = 1.f / sum;
            for (int j2 = 0; j2 < 40; ++j2) row[j2] *= inv;
        }
        __syncthreads();

        // -------- PV: outh[40][32], store into s_q region --------
        {
            float a5[5] = {0, 0, 0, 0, 0};
            for (int kk = 0; kk < 40; kk += 4) {
                float v0 = s_v[(kk + 0) * 32 + ct];
                float v1 = s_v[(kk + 1) * 32 + ct];
                float v2 = s_v[(kk + 2) * 32 + ct];
                float v3 = s_v[(kk + 3) * 32 + ct];
                #pragma unroll
                for (int r = 0; r < 5; ++r) {
                    float4 a = *(const float4*)(s_attn + (i0 + r) * 40 + kk);
                    a5[r] += a.x * v0 + a.y * v1 + a.z * v2 + a.w * v3;
                }
            }
            #pragma unroll
            for (int r = 0; r < 5; ++r) s_q[(i0 + r) * 32 + ct] = a5[r];
        }
        __syncthreads();  // outh visible; s_w free

        // -------- stage proj_w rows [h*32, h*32+32) x 256 --------
        #pragma unroll
        for (int rep = 0; rep < 8; ++rep) {
            int f = tid + rep * 256;          // float4 units, 2048 total
            int rr = f >> 6, j4 = (f & 63) * 4;
            *(float4*)(s_w + rr * 256 + j4) =
                *(const float4*)(proj_w + (size_t)(h * 32 + rr) * 256 + j4);
        }
        __syncthreads();

        // -------- proj partial: accO += outh @ proj_w[h*32.., :] --------
        for (int d = 0; d < 32; d += 4) {
            float4 a[5];
            #pragma unroll
            for (int r = 0; r < 5; ++r) a[r] = *(const float4*)(s_q + (i0 + r) * 32 + d);
            #pragma unroll
            for (int m = 0; m < 8; ++m) {
                float w0 = s_w[(d + 0) * 256 + ct + 32 * m];
                float w1 = s_w[(d + 1) * 256 + ct + 32 * m];
                float w2 = s_w[(d + 2) * 256 + ct + 32 * m];
                float w3 = s_w[(d + 3) * 256 + ct + 32 * m];
                #pragma unroll
                for (int r = 0; r < 5; ++r)
                    accO[r][m] += a[r].x * w0 + a[r].y * w1 + a[r].z * w2 + a[r].w * w3;
            }
        }
        __syncthreads();  // before next head's staging overwrites s_w / stores overwrite s_q
    }

    // ---------------- write output ----------------
    #pragma unroll
    for (int m = 0; m < 8; ++m) {
        float pb = proj_b[ct + 32 * m];
        #pragma unroll
        for (int r = 0; r < 5; ++r)
            out[(size_t)w * 10240 + (i0 + r) * 256 + ct + 32 * m] = accO[r][m] + pb;
    }
}

__global__ void octa_std(const float* __restrict__ ws, float* __restrict__ out,
                         int total_rows, size_t off)
{
    int j = blockIdx.x * 256 + threadIdx.x;
    if (j < 768) {
        float s = ws[j], ss = ws[768 + j];
        float T = (float)total_rows;
        float var = (ss - s * s / T) / (T - 1.f);
        out[off + j] = sqrtf(fmaxf(var, 0.f));
    }
}

extern "C" void kernel_launch(void* const* d_in, const int* in_sizes, int n_in,
                              void* d_out, int out_size, void* d_ws, size_t ws_size,
                              hipStream_t stream) {
    const float* data     = (const float*)d_in[0];
    const int*   rel_pos  = (const int*)d_in[1];
    const float* mask     = (const float*)d_in[2];
    const float* qkv_w    = (const float*)d_in[3];
    const float* qkv_b    = (const float*)d_in[4];
    const float* proj_w   = (const float*)d_in[5];
    const float* proj_b   = (const float*)d_in[6];
    const float* rpe_tab  = (const float*)d_in[7];
    float* out = (float*)d_out;
    float* ws  = (float*)d_ws;

    const int nw = in_sizes[1] / 3072;          // 4096
    const int total_rows = nw * 40;             // 163840
    const size_t std_off = (size_t)nw * 10240;  // 41943040

    // zero std accumulators every launch (graph replays don't re-poison ws)
    hipMemsetAsync(ws, 0, 1536 * sizeof(float), stream);

    static const size_t lds_bytes = 29800 * sizeof(float);  // 119200
    (void)hipFuncSetAttribute((const void*)octa_main,
                              hipFuncAttributeMaxDynamicSharedMemorySize,
                              (int)lds_bytes);

    hipLaunchKernelGGL(octa_main, dim3(nw), dim3(256), lds_bytes, stream,
                       data, rel_pos, mask, qkv_w, qkv_b, proj_w, proj_b, rpe_tab,
                       ws, out);
    hipLaunchKernelGGL(octa_std, dim3(3), dim3(256), 0, stream, ws, out,
                       total_rows, std_off);
}

// Round 3
// 652.361 us; speedup vs baseline: 6.5341x; 6.5341x over previous
//
#include <hip/hip_runtime.h>
#include <math.h>

// OctreeAttention: C=256, H=8, HD=32, K=32, G=8, W=40 (pad 48), NW=4096, RPE rows=153
#define SCALE_F 0.17677669529663687f  // 32^-0.5

typedef __bf16 bf16x8 __attribute__((ext_vector_type(8)));
typedef float f32x4 __attribute__((ext_vector_type(4)));

// ---- LDS map (bytes), total 154400 <= 163840 ----
// O_RPE: rpe table f32 [153*8]                     = 4896
// O_A  : s_a/s_o bf16 [48][256], swz ^((row&7)<<4) = 24576
// O_ATT: per-wave attn buffers 8 * 15616 = 124928
//        (aliased by GEMM1 B-chunks [768][32]=49152 and GEMM2 B [256][32]=16384)
#define O_RPE 0
#define O_A   4896
#define O_ATT 29472
#define ATT_STRIDE 15616
#define AQ 0        // q  [48][40bf16] rows 80B
#define AK 3840     // k  same
#define AV 7680     // vT [32][64bf16] rows 128B, swz ^((d&7)<<4)
#define AP 11776    // P  [48][40bf16] rows 80B (two K-halves)
#define LDS_BYTES 154400

__device__ __forceinline__ unsigned short f2bf(float f) {
  unsigned u = __builtin_bit_cast(unsigned, f);
  u = (u + 0x7FFFu + ((u >> 16) & 1u)) >> 16;
  return (unsigned short)u;
}
__device__ __forceinline__ bf16x8 ld16(const void* p) {
  int4 v = *(const int4*)p;
  return __builtin_bit_cast(bf16x8, v);
}
// s_a/s_o addressing: row stride 512B, XOR-swizzle bits 4-6 with row&7
__device__ __forceinline__ int a_addr(int row, int byte) {
  return O_A + row * 512 + (byte ^ ((row & 7) << 4));
}
// staged-B addressing: row (= output col n) stride 64B, XOR bits 4-5 with n&3
__device__ __forceinline__ int b_addr(int n, int byte) {
  return O_ATT + n * 64 + (byte ^ ((n & 3) << 4));
}
// vT addressing: row d stride 128B, XOR bits 4-6 with d&7
__device__ __forceinline__ int v_addr(int d, int byte) {
  return AV + d * 128 + (byte ^ ((d & 7) << 4));
}

// ---------------- pre-kernel: transpose+convert weights to bf16 ----------------
__global__ void octa_prep(const float* __restrict__ qkv_w, const float* __restrict__ proj_w,
                          unsigned short* __restrict__ wTq, unsigned short* __restrict__ pTq)
{
  int idx = blockIdx.x * 256 + threadIdx.x;   // 262144 total
  if (idx < 196608) {                         // qkv_wT[n=768][k=256]
    int n = idx >> 8, k = idx & 255;
    wTq[idx] = f2bf(qkv_w[k * 768 + n]);
  } else {
    int i = idx - 196608;                     // proj_wT[n=256][k=256]
    int n = i >> 8, k = i & 255;
    pTq[i] = f2bf(proj_w[k * 256 + n]);
  }
}

// ---------------- main fused kernel: 1 window / block, 8 waves ----------------
__global__ __launch_bounds__(512, 2)
void octa_main(const float* __restrict__ data, const int* __restrict__ rel_pos,
               const float* __restrict__ maskp, const float* __restrict__ qkv_b,
               const float* __restrict__ proj_b, const float* __restrict__ rpe_table,
               const unsigned short* __restrict__ wTq, const unsigned short* __restrict__ pTq,
               float* __restrict__ ws, float* __restrict__ out)
{
  extern __shared__ char smem[];
  float* s_rpe = (float*)(smem + O_RPE);

  const int tid = threadIdx.x;
  const int w   = blockIdx.x;
  const int wid = tid >> 6;         // wave id = head id
  const int lane = tid & 63;
  const int ql = lane & 15;         // "col" lane within MFMA tile
  const int lg = lane >> 4;         // lane group 0..3
  const int h  = wid;
  const int ab = O_ATT + wid * ATT_STRIDE;

  // ---- phase 0: stage rpe table + window data (fp32 -> bf16, swizzled) ----
  for (int f = tid; f < 1224; f += 512) s_rpe[f] = rpe_table[f];
  {
    const float4* src = (const float4*)(data + (size_t)w * 10240);
    for (int f = tid; f < 2560; f += 512) {       // 40 rows * 64 float4
      int token = f >> 6, q4 = f & 63;
      float4 d4 = src[f];
      uint2 pk;
      pk.x = (unsigned)f2bf(d4.x) | ((unsigned)f2bf(d4.y) << 16);
      pk.y = (unsigned)f2bf(d4.z) | ((unsigned)f2bf(d4.w) << 16);
      *(uint2*)(smem + a_addr(token, q4 * 8)) = pk;
    }
    // zero pad rows 40..47
    int token = 40 + (tid >> 6), byte = (tid & 63) * 8;
    *(uint2*)(smem + a_addr(token, byte)) = make_uint2(0u, 0u);
  }

  // ---- GEMM1: qkv = data @ qkv_w  (48x768, K=256), wave w owns head w's 6 n-tiles ----
  f32x4 acc[18];
  #pragma unroll
  for (int i = 0; i < 18; ++i) acc[i] = (f32x4){0.f, 0.f, 0.f, 0.f};

  for (int kc = 0; kc < 8; ++kc) {
    __syncthreads();
    // stage B chunk: wT[n=768][k = kc*32 .. +32] -> [768][32] bf16, swizzled
    for (int g = tid; g < 3072; g += 512) {
      int n = g >> 2, gk = (g & 3) * 16;
      int4 t = *(const int4*)((const char*)wTq + (size_t)n * 512 + kc * 64 + gk);
      *(int4*)(smem + b_addr(n, gk)) = t;
    }
    __syncthreads();
    bf16x8 af[3];
    #pragma unroll
    for (int mt = 0; mt < 3; ++mt)
      af[mt] = ld16(smem + a_addr(mt * 16 + ql, kc * 64 + lg * 16));
    #pragma unroll
    for (int j = 0; j < 6; ++j) {
      int nt = (j >> 1) * 16 + 2 * wid + (j & 1);
      bf16x8 bf = ld16(smem + b_addr(nt * 16 + ql, lg * 16));
      #pragma unroll
      for (int mt = 0; mt < 3; ++mt)
        acc[j * 3 + mt] = __builtin_amdgcn_mfma_f32_16x16x32_bf16(af[mt], bf, acc[j * 3 + mt], 0, 0, 0);
    }
  }
  __syncthreads();   // all waves done reading staged B -> attn region writable

  // ---- bias + std partials + write q/k/vT bf16 into this wave's buffers ----
  #pragma unroll
  for (int j = 0; j < 6; ++j) {
    int sec = j >> 1;
    int ncol = sec * 256 + 32 * wid + (j & 1) * 16 + ql;
    int d = (j & 1) * 16 + ql;
    float bias = qkv_b[ncol];
    float s1 = 0.f, s2 = 0.f;
    #pragma unroll
    for (int mt = 0; mt < 3; ++mt) {
      #pragma unroll
      for (int r = 0; r < 4; ++r) {
        int token = mt * 16 + lg * 4 + r;
        float v = acc[j * 3 + mt][r] + bias;
        if (token < 40) { s1 += v; s2 += v * v; }
        if (sec == 0)
          *(unsigned short*)(smem + ab + AQ + token * 80 + d * 2) = f2bf(v * SCALE_F);
        else if (sec == 1)
          *(unsigned short*)(smem + ab + AK + token * 80 + d * 2) = f2bf(v);
        else
          *(unsigned short*)(smem + ab + v_addr(d, token * 2)) = f2bf(v);
      }
    }
    s1 += __shfl_xor(s1, 16); s1 += __shfl_xor(s1, 32);
    s2 += __shfl_xor(s2, 16); s2 += __shfl_xor(s2, 32);
    if (lg == 0) { atomicAdd(ws + ncol, s1); atomicAdd(ws + 768 + ncol, s2); }
  }
  // zero-fill vT tokens 48..63 (PV half-2 contracts over kj 32..63)
  {
    int zd = lane >> 1;
    int zb = 96 + (lane & 1) * 16;
    *(int4*)(smem + ab + v_addr(zd, zb)) = (int4){0, 0, 0, 0};
  }
  asm volatile("" ::: "memory");   // order ushort stores before int4 fragment loads

  // ---- attention for head h = wid (fully wave-private, no barriers) ----
  // ST[kj][qi] = mfma(A=k, B=q)  (q already scaled)
  f32x4 st[9];
  {
    bf16x8 kf[3], qf[3];
    #pragma unroll
    for (int a = 0; a < 3; ++a) kf[a] = ld16(smem + ab + AK + (a * 16 + ql) * 80 + lg * 16);
    #pragma unroll
    for (int b = 0; b < 3; ++b) qf[b] = ld16(smem + ab + AQ + (b * 16 + ql) * 80 + lg * 16);
    #pragma unroll
    for (int a = 0; a < 3; ++a)
      #pragma unroll
      for (int b = 0; b < 3; ++b)
        st[a * 3 + b] = __builtin_amdgcn_mfma_f32_16x16x32_bf16(
            kf[a], qf[b], (f32x4){0.f, 0.f, 0.f, 0.f}, 0, 0, 0);
  }

  // logits: + mask + rpe; per-COLUMN (qi) max & sum: one per b-tile
  float mx[3] = {-3e38f, -3e38f, -3e38f};
  #pragma unroll
  for (int a = 0; a < 3; ++a) {
    #pragma unroll
    for (int b = 0; b < 3; ++b) {
      #pragma unroll
      for (int r = 0; r < 4; ++r) {
        int kj = a * 16 + lg * 4 + r;
        int qi = b * 16 + ql;
        float s = st[a * 3 + b][r];
        if (kj < 40) {
          if (qi < 40) {
            s += maskp[(size_t)w * 1600 + qi * 40 + kj];
            if (kj >= 8 && qi >= 8) {
              const int* rp = rel_pos + ((size_t)w * 1024 + (qi - 8) * 32 + (kj - 8)) * 3;
              int c0 = rp[0], c1 = rp[1], c2 = rp[2];
              c0 = min(25, max(-25, c0));
              c1 = min(25, max(-25, c1));
              c2 = min(25, max(-25, c2));
              s += s_rpe[(c0 + 25) * 8 + h] + s_rpe[(c1 + 76) * 8 + h] + s_rpe[(c2 + 127) * 8 + h];
            }
          }
        } else {
          s = -1e30f;   // padded key -> excluded
        }
        st[a * 3 + b][r] = s;
        mx[b] = fmaxf(mx[b], s);
      }
    }
  }
  #pragma unroll
  for (int b = 0; b < 3; ++b) {
    mx[b] = fmaxf(mx[b], __shfl_xor(mx[b], 16));
    mx[b] = fmaxf(mx[b], __shfl_xor(mx[b], 32));
  }
  float sum[3] = {0.f, 0.f, 0.f};
  #pragma unroll
  for (int a = 0; a < 3; ++a)
    #pragma unroll
    for (int b = 0; b < 3; ++b)
      #pragma unroll
      for (int r = 0; r < 4; ++r) {
        float e = __expf(st[a * 3 + b][r] - mx[b]);
        st[a * 3 + b][r] = e;
        sum[b] += e;
      }
  float inv[3];
  #pragma unroll
  for (int b = 0; b < 3; ++b) {
    sum[b] += __shfl_xor(sum[b], 16);
    sum[b] += __shfl_xor(sum[b], 32);
    inv[b] = 1.f / sum[b];
  }

  // PV in two K-halves: OT[d][qi] = mfma(A=vT, B=P)
  f32x4 ot[6];
  #pragma unroll
  for (int i = 0; i < 6; ++i) ot[i] = (f32x4){0.f, 0.f, 0.f, 0.f};

  // P half 1: kj 0..31
  #pragma unroll
  for (int a = 0; a < 2; ++a)
    #pragma unroll
    for (int b = 0; b < 3; ++b)
      #pragma unroll
      for (int r = 0; r < 4; ++r) {
        int kj = a * 16 + lg * 4 + r, qi = b * 16 + ql;
        *(unsigned short*)(smem + ab + AP + qi * 80 + kj * 2) = f2bf(st[a * 3 + b][r] * inv[b]);
      }
  asm volatile("" ::: "memory");   // P stores before pf loads
  {
    bf16x8 vf0 = ld16(smem + ab + v_addr(0 * 16 + ql, lg * 16));
    bf16x8 vf1 = ld16(smem + ab + v_addr(1 * 16 + ql, lg * 16));
    #pragma unroll
    for (int b = 0; b < 3; ++b) {
      bf16x8 pf = ld16(smem + ab + AP + (b * 16 + ql) * 80 + lg * 16);
      ot[0 * 3 + b] = __builtin_amdgcn_mfma_f32_16x16x32_bf16(vf0, pf, ot[0 * 3 + b], 0, 0, 0);
      ot[1 * 3 + b] = __builtin_amdgcn_mfma_f32_16x16x32_bf16(vf1, pf, ot[1 * 3 + b], 0, 0, 0);
    }
  }
  asm volatile("" ::: "memory");   // pf loads (half1) before P half2 stores (WAR)
  // P half 2: kj 32..47 real (40..47 = exp(-1e30)=0), kj 48..63 explicit zeros
  #pragma unroll
  for (int b = 0; b < 3; ++b) {
    int qi = b * 16 + ql;
    #pragma unroll
    for (int r = 0; r < 4; ++r) {
      int kj = 32 + lg * 4 + r;
      *(unsigned short*)(smem + ab + AP + qi * 80 + (kj - 32) * 2) = f2bf(st[6 + b][r] * inv[b]);
    }
    *(uint2*)(smem + ab + AP + qi * 80 + 32 + lg * 8) = make_uint2(0u, 0u);
  }
  asm volatile("" ::: "memory");   // P half2 stores before pf loads
  {
    bf16x8 vf0 = ld16(smem + ab + v_addr(0 * 16 + ql, 64 + lg * 16));
    bf16x8 vf1 = ld16(smem + ab + v_addr(1 * 16 + ql, 64 + lg * 16));
    #pragma unroll
    for (int b = 0; b < 3; ++b) {
      bf16x8 pf = ld16(smem + ab + AP + (b * 16 + ql) * 80 + lg * 16);
      ot[0 * 3 + b] = __builtin_amdgcn_mfma_f32_16x16x32_bf16(vf0, pf, ot[0 * 3 + b], 0, 0, 0);
      ot[1 * 3 + b] = __builtin_amdgcn_mfma_f32_16x16x32_bf16(vf1, pf, ot[1 * 3 + b], 0, 0, 0);
    }
  }
  // write O to s_o (aliases s_a): s_o[qi][h*32+d] bf16, swizzled like s_a
  #pragma unroll
  for (int dm = 0; dm < 2; ++dm)
    #pragma unroll
    for (int b = 0; b < 3; ++b)
      #pragma unroll
      for (int r = 0; r < 4; ++r) {
        int d = dm * 16 + lg * 4 + r;
        int qi = b * 16 + ql;
        *(unsigned short*)(smem + a_addr(qi, (h * 32 + d) * 2)) = f2bf(ot[dm * 3 + b][r]);
      }

  // ---- GEMM2: out = O @ proj_w  (48x256, K=256) ----
  f32x4 oacc[6];
  #pragma unroll
  for (int i = 0; i < 6; ++i) oacc[i] = (f32x4){0.f, 0.f, 0.f, 0.f};

  for (int kc = 0; kc < 8; ++kc) {
    __syncthreads();   // first iter: all waves done with attn region + s_o written
    for (int g = tid; g < 1024; g += 512) {
      int n = g >> 2, gk = (g & 3) * 16;
      int4 t = *(const int4*)((const char*)pTq + (size_t)n * 512 + kc * 64 + gk);
      *(int4*)(smem + b_addr(n, gk)) = t;
    }
    __syncthreads();
    bf16x8 af[3];
    #pragma unroll
    for (int mt = 0; mt < 3; ++mt)
      af[mt] = ld16(smem + a_addr(mt * 16 + ql, kc * 64 + lg * 16));
    #pragma unroll
    for (int nt = 0; nt < 2; ++nt) {
      bf16x8 bf = ld16(smem + b_addr((2 * wid + nt) * 16 + ql, lg * 16));
      #pragma unroll
      for (int mt = 0; mt < 3; ++mt)
        oacc[nt * 3 + mt] = __builtin_amdgcn_mfma_f32_16x16x32_bf16(af[mt], bf, oacc[nt * 3 + mt], 0, 0, 0);
    }
  }

  // epilogue: + proj_b, store fp32 (real tokens only)
  #pragma unroll
  for (int nt = 0; nt < 2; ++nt) {
    int ncol = (2 * wid + nt) * 16 + ql;
    float pb = proj_b[ncol];
    #pragma unroll
    for (int mt = 0; mt < 3; ++mt)
      #pragma unroll
      for (int r = 0; r < 4; ++r) {
        int token = mt * 16 + lg * 4 + r;
        if (token < 40)
          out[(size_t)w * 10240 + token * 256 + ncol] = oacc[nt * 3 + mt][r] + pb;
      }
  }
}

__global__ void octa_std(const float* __restrict__ ws, float* __restrict__ out,
                         int total_rows, size_t off)
{
  int j = blockIdx.x * 256 + threadIdx.x;
  if (j < 768) {
    float s = ws[j], ss = ws[768 + j];
    float T = (float)total_rows;
    float var = (ss - s * s / T) / (T - 1.f);
    out[off + j] = sqrtf(fmaxf(var, 0.f));
  }
}

extern "C" void kernel_launch(void* const* d_in, const int* in_sizes, int n_in,
                              void* d_out, int out_size, void* d_ws, size_t ws_size,
                              hipStream_t stream) {
  const float* data    = (const float*)d_in[0];
  const int*   rel_pos = (const int*)d_in[1];
  const float* maskp   = (const float*)d_in[2];
  const float* qkv_w   = (const float*)d_in[3];
  const float* qkv_b   = (const float*)d_in[4];
  const float* proj_w  = (const float*)d_in[5];
  const float* proj_b  = (const float*)d_in[6];
  const float* rpe_tab = (const float*)d_in[7];
  float* out = (float*)d_out;
  float* ws  = (float*)d_ws;

  const int nw = in_sizes[1] / 3072;           // 4096
  const int total_rows = nw * 40;
  const size_t std_off = (size_t)nw * 10240;

  // ws layout: [0,1536) f32 std sums; bf16 qkv_wT at +6144B (384KB); proj_wT after (128KB)
  unsigned short* wTq = (unsigned short*)((char*)d_ws + 6144);
  unsigned short* pTq = (unsigned short*)((char*)d_ws + 6144 + 393216);

  hipMemsetAsync(ws, 0, 6144, stream);
  hipLaunchKernelGGL(octa_prep, dim3(1024), dim3(256), 0, stream, qkv_w, proj_w, wTq, pTq);

  (void)hipFuncSetAttribute((const void*)octa_main,
                            hipFuncAttributeMaxDynamicSharedMemorySize, LDS_BYTES);
  hipLaunchKernelGGL(octa_main, dim3(nw), dim3(512), LDS_BYTES, stream,
                     data, rel_pos, maskp, qkv_b, proj_b, rpe_tab, wTq, pTq, ws, out);
  hipLaunchKernelGGL(octa_std, dim3(3), dim3(256), 0, stream, ws, out, total_rows, std_off);
}

// Round 4
// 464.480 us; speedup vs baseline: 9.1771x; 1.4045x over previous
//
#include <hip/hip_runtime.h>
#include <math.h>

// OctreeAttention: C=256, H=8, HD=32, K=32, G=8, W=40 (pad 48), NW=4096, RPE rows=153
#define SCALE_F 0.17677669529663687f  // 32^-0.5

typedef __bf16 bf16x8 __attribute__((ext_vector_type(8)));
typedef float f32x4 __attribute__((ext_vector_type(4)));

// ---- LDS map (bytes), total 163744 <= 163840 ----
#define O_RPE 0        // rpe table f32 [153*8] = 4896
#define O_MSK 4896     // mask bf16 [40][40] = 3200
#define O_IDX 8096     // packed rpe idx uint [1024], swz = 4096
#define O_A   12192    // s_a/s_o bf16 [48][256] rows 512B, swz ^((row&7)<<4) = 24576
#define O_ATT 36768    // region: GEMM1 staged B dbuf / per-wave attn bufs / GEMM2 staged B
// GEMM1 staged B: [768][32]bf16 rows 64B, swz ^((n&3)<<4); dbuf at O_ATT+0 / O_ATT+49152
#define B1_SZ 49152
// attn per-wave stride 11776: QP@0 (q, then P) [48]x80B, K@3840 [48]x80B, V@7680 [32]x128B swz
#define ATT_STRIDE 11776
#define AK 3840
#define AV 7680
// GEMM2 staged B: [256][64]bf16 rows 128B, swz ^((n&7)<<4); S-buf in spare, A-buf aliases attn
#define B2_S (O_ATT + 94208)   // abs 130976, +32768 = 163744
#define B2_A O_ATT
#define LDS_BYTES 163744

__device__ __forceinline__ unsigned short f2bf(float f) {
  unsigned u = __builtin_bit_cast(unsigned, f);
  u = (u + 0x7FFFu + ((u >> 16) & 1u)) >> 16;
  return (unsigned short)u;
}
__device__ __forceinline__ float bf2f(unsigned short u) {
  return __builtin_bit_cast(float, (unsigned)u << 16);
}
__device__ __forceinline__ bf16x8 ld16(const void* p) {
  int4 v = *(const int4*)p;
  return __builtin_bit_cast(bf16x8, v);
}
// async global->LDS, 16B per lane; LDS dest = wave-uniform base + lane*16
__device__ __forceinline__ void gll16(const void* g, void* l) {
  __builtin_amdgcn_global_load_lds(
      (const __attribute__((address_space(1))) unsigned int*)g,
      (__attribute__((address_space(3))) unsigned int*)l, 16, 0, 0);
}
__device__ __forceinline__ int a_addr(int row, int byte) {
  return O_A + row * 512 + (byte ^ ((row & 7) << 4));
}
__device__ __forceinline__ int v_addr(int d, int byte) {   // within wave attn buf
  return AV + d * 128 + (byte ^ ((d & 7) << 4));
}

// ---------------- pre-kernel: transpose+convert weights to bf16 ----------------
__global__ void octa_prep(const float* __restrict__ qkv_w, const float* __restrict__ proj_w,
                          unsigned short* __restrict__ wTq, unsigned short* __restrict__ pTq)
{
  int idx = blockIdx.x * 256 + threadIdx.x;   // 262144 total
  if (idx < 196608) {                         // qkv_wT[n=768][k=256]
    int n = idx >> 8, k = idx & 255;
    wTq[idx] = f2bf(qkv_w[k * 768 + n]);
  } else {
    int i = idx - 196608;                     // proj_wT[n=256][k=256]
    int n = i >> 8, k = i & 255;
    pTq[i] = f2bf(proj_w[k * 256 + n]);
  }
}

// ---------------- main fused kernel: 1 window / block, 8 waves ----------------
__global__ __launch_bounds__(512, 2)
void octa_main(const float* __restrict__ data, const int* __restrict__ rel_pos,
               const float* __restrict__ maskp, const float* __restrict__ qkv_b,
               const float* __restrict__ proj_b, const float* __restrict__ rpe_table,
               const unsigned short* __restrict__ wTq, const unsigned short* __restrict__ pTq,
               float* __restrict__ ws, float* __restrict__ out)
{
  extern __shared__ char smem[];
  float* s_rpe = (float*)(smem + O_RPE);

  const int tid = threadIdx.x;
  const int w   = blockIdx.x;
  const int wid = tid >> 6;         // wave id = head id
  const int lane = tid & 63;
  const int ql = lane & 15;
  const int lg = lane >> 4;
  const int h  = wid;
  const int ab = O_ATT + wid * ATT_STRIDE;

  // ---- issue GEMM1 chunk-0 staging first (latency hides under phase-0 VALU work) ----
  {
    #pragma unroll
    for (int it = 0; it < 6; ++it) {
      int g = it * 512 + tid;
      int n = g >> 2, slot = g & 3;
      const char* src = (const char*)wTq + (size_t)n * 512 + ((slot * 16) ^ ((n & 3) << 4));
      gll16(src, smem + O_ATT + it * 8192 + wid * 1024);
    }
  }

  // ---- phase 0: stage rpe table, mask(bf16), packed idx, window data (bf16, swz) ----
  for (int f = tid; f < 1224; f += 512) s_rpe[f] = rpe_table[f];
  for (int f = tid; f < 400; f += 512) {          // mask: 1600 f32 -> bf16 [40][40]
    float4 m4 = ((const float4*)(maskp + (size_t)w * 1600))[f];
    uint2 pk;
    pk.x = (unsigned)f2bf(m4.x) | ((unsigned)f2bf(m4.y) << 16);
    pk.y = (unsigned)f2bf(m4.z) | ((unsigned)f2bf(m4.w) << 16);
    *(uint2*)(smem + O_MSK + f * 8) = pk;
  }
  for (int p = tid; p < 1024; p += 512) {         // rel_pos: clamp + pack 3x10 bits
    const int* rp = rel_pos + ((size_t)w * 1024 + p) * 3;
    int c0 = rp[0], c1 = rp[1], c2 = rp[2];
    c0 = min(25, max(-25, c0)); c1 = min(25, max(-25, c1)); c2 = min(25, max(-25, c2));
    unsigned pk = (unsigned)(c0 + 25) | ((unsigned)(c1 + 76) << 10) | ((unsigned)(c2 + 127) << 20);
    *(unsigned*)(smem + O_IDX + ((p * 4) ^ (((p >> 5) & 7) << 4))) = pk;
  }
  {
    const float4* src = (const float4*)(data + (size_t)w * 10240);
    for (int f = tid; f < 2560; f += 512) {       // 40 rows * 64 float4 -> bf16 s_a
      int token = f >> 6, q4 = f & 63;
      float4 d4 = src[f];
      uint2 pk;
      pk.x = (unsigned)f2bf(d4.x) | ((unsigned)f2bf(d4.y) << 16);
      pk.y = (unsigned)f2bf(d4.z) | ((unsigned)f2bf(d4.w) << 16);
      *(uint2*)(smem + a_addr(token, q4 * 8)) = pk;
    }
    int token = 40 + (tid >> 6), byte = (tid & 63) * 8;   // zero pad rows 40..47
    *(uint2*)(smem + a_addr(token, byte)) = make_uint2(0u, 0u);
  }
  __syncthreads();   // drains vmcnt(0): chunk-0 staged; phase-0 LDS visible

  // ---- GEMM1: qkv = data @ qkv_w (48x768, K=256), 8 chunks K=32, dbuf pipeline ----
  f32x4 acc[18];
  #pragma unroll
  for (int i = 0; i < 18; ++i) acc[i] = (f32x4){0.f, 0.f, 0.f, 0.f};

  for (int t = 0; t < 8; ++t) {
    if (t < 7) {      // issue next chunk into other buffer
      int bb = O_ATT + ((t + 1) & 1) * B1_SZ;
      #pragma unroll
      for (int it = 0; it < 6; ++it) {
        int g = it * 512 + tid;
        int n = g >> 2, slot = g & 3;
        const char* src = (const char*)wTq + (size_t)n * 512 + (t + 1) * 64
                          + ((slot * 16) ^ ((n & 3) << 4));
        gll16(src, smem + bb + it * 8192 + wid * 1024);
      }
    }
    const int bb = O_ATT + (t & 1) * B1_SZ;
    bf16x8 af[3];
    #pragma unroll
    for (int mt = 0; mt < 3; ++mt)
      af[mt] = ld16(smem + a_addr(mt * 16 + ql, t * 64 + lg * 16));
    #pragma unroll
    for (int j = 0; j < 6; ++j) {
      int n = ((j >> 1) * 16 + 2 * wid + (j & 1)) * 16 + ql;
      bf16x8 bf = ld16(smem + bb + n * 64 + ((lg * 16) ^ ((n & 3) << 4)));
      #pragma unroll
      for (int mt = 0; mt < 3; ++mt)
        acc[j * 3 + mt] = __builtin_amdgcn_mfma_f32_16x16x32_bf16(af[mt], bf, acc[j * 3 + mt], 0, 0, 0);
    }
    __syncthreads();  // drains this iter's stage loads; all waves done reading buf[t]
  }

  // ---- prestage GEMM2 chunk 0 into spare region (hides under attention) ----
  {
    #pragma unroll
    for (int it = 0; it < 4; ++it) {
      int g = it * 512 + tid;
      int n = g >> 3, slot = g & 7;
      const char* src = (const char*)pTq + (size_t)n * 512 + ((slot * 16) ^ ((n & 7) << 4));
      gll16(src, smem + B2_S + it * 8192 + wid * 1024);
    }
  }

  // ---- bias + std partials + write q/k/vT bf16 into this wave's attn buffer ----
  #pragma unroll
  for (int j = 0; j < 6; ++j) {
    int sec = j >> 1;
    int ncol = sec * 256 + 32 * wid + (j & 1) * 16 + ql;
    int d = (j & 1) * 16 + ql;
    float bias = qkv_b[ncol];
    float s1 = 0.f, s2 = 0.f;
    #pragma unroll
    for (int mt = 0; mt < 3; ++mt) {
      #pragma unroll
      for (int r = 0; r < 4; ++r) {
        int token = mt * 16 + lg * 4 + r;
        float v = acc[j * 3 + mt][r] + bias;
        if (token < 40) { s1 += v; s2 += v * v; }
        if (sec == 0)
          *(unsigned short*)(smem + ab + token * 80 + d * 2) = f2bf(v * SCALE_F);
        else if (sec == 1)
          *(unsigned short*)(smem + ab + AK + token * 80 + d * 2) = f2bf(v);
        else
          *(unsigned short*)(smem + ab + v_addr(d, token * 2)) = f2bf(v);
      }
    }
    s1 += __shfl_xor(s1, 16); s1 += __shfl_xor(s1, 32);
    s2 += __shfl_xor(s2, 16); s2 += __shfl_xor(s2, 32);
    if (lg == 0) { atomicAdd(ws + ncol, s1); atomicAdd(ws + 768 + ncol, s2); }
  }
  // zero-fill vT tokens 48..63
  {
    int zd = lane >> 1;
    int zb = 96 + (lane & 1) * 16;
    *(int4*)(smem + ab + v_addr(zd, zb)) = (int4){0, 0, 0, 0};
  }
  asm volatile("" ::: "memory");

  // ---- attention for head h = wid (wave-private) ----
  f32x4 st[9];
  {
    bf16x8 kf[3], qf[3];
    #pragma unroll
    for (int a = 0; a < 3; ++a) kf[a] = ld16(smem + ab + AK + (a * 16 + ql) * 80 + lg * 16);
    #pragma unroll
    for (int b = 0; b < 3; ++b) qf[b] = ld16(smem + ab + (b * 16 + ql) * 80 + lg * 16);
    #pragma unroll
    for (int a = 0; a < 3; ++a)
      #pragma unroll
      for (int b = 0; b < 3; ++b)
        st[a * 3 + b] = __builtin_amdgcn_mfma_f32_16x16x32_bf16(
            kf[a], qf[b], (f32x4){0.f, 0.f, 0.f, 0.f}, 0, 0, 0);
  }

  // logits from LDS: + mask(bf16) + rpe (packed idx); per-qi-column max/sum
  float mx[3] = {-3e38f, -3e38f, -3e38f};
  #pragma unroll
  for (int a = 0; a < 3; ++a) {
    #pragma unroll
    for (int b = 0; b < 3; ++b) {
      #pragma unroll
      for (int r = 0; r < 4; ++r) {
        int kj = a * 16 + lg * 4 + r;
        int qi = b * 16 + ql;
        float s = st[a * 3 + b][r];
        if (kj < 40) {
          if (qi < 40) {
            s += bf2f(*(const unsigned short*)(smem + O_MSK + (qi * 40 + kj) * 2));
            if (kj >= 8 && qi >= 8) {
              int p = (qi - 8) * 32 + (kj - 8);
              unsigned pk = *(const unsigned*)(smem + O_IDX + ((p * 4) ^ (((p >> 5) & 7) << 4)));
              s += s_rpe[(pk & 1023) * 8 + h] + s_rpe[((pk >> 10) & 1023) * 8 + h]
                 + s_rpe[(pk >> 20) * 8 + h];
            }
          }
        } else {
          s = -1e30f;
        }
        st[a * 3 + b][r] = s;
        mx[b] = fmaxf(mx[b], s);
      }
    }
  }
  #pragma unroll
  for (int b = 0; b < 3; ++b) {
    mx[b] = fmaxf(mx[b], __shfl_xor(mx[b], 16));
    mx[b] = fmaxf(mx[b], __shfl_xor(mx[b], 32));
  }
  float sum[3] = {0.f, 0.f, 0.f};
  #pragma unroll
  for (int a = 0; a < 3; ++a)
    #pragma unroll
    for (int b = 0; b < 3; ++b)
      #pragma unroll
      for (int r = 0; r < 4; ++r) {
        float e = __expf(st[a * 3 + b][r] - mx[b]);
        st[a * 3 + b][r] = e;
        sum[b] += e;
      }
  float inv[3];
  #pragma unroll
  for (int b = 0; b < 3; ++b) {
    sum[b] += __shfl_xor(sum[b], 16);
    sum[b] += __shfl_xor(sum[b], 32);
    inv[b] = 1.f / sum[b];
  }

  // PV in two K-halves; P aliases Q region (q consumed)
  f32x4 ot[6];
  #pragma unroll
  for (int i = 0; i < 6; ++i) ot[i] = (f32x4){0.f, 0.f, 0.f, 0.f};

  #pragma unroll
  for (int a = 0; a < 2; ++a)
    #pragma unroll
    for (int b = 0; b < 3; ++b)
      #pragma unroll
      for (int r = 0; r < 4; ++r) {
        int kj = a * 16 + lg * 4 + r, qi = b * 16 + ql;
        *(unsigned short*)(smem + ab + qi * 80 + kj * 2) = f2bf(st[a * 3 + b][r] * inv[b]);
      }
  asm volatile("" ::: "memory");
  {
    bf16x8 vf0 = ld16(smem + ab + v_addr(ql, lg * 16));
    bf16x8 vf1 = ld16(smem + ab + v_addr(16 + ql, lg * 16));
    #pragma unroll
    for (int b = 0; b < 3; ++b) {
      bf16x8 pf = ld16(smem + ab + (b * 16 + ql) * 80 + lg * 16);
      ot[b] = __builtin_amdgcn_mfma_f32_16x16x32_bf16(vf0, pf, ot[b], 0, 0, 0);
      ot[3 + b] = __builtin_amdgcn_mfma_f32_16x16x32_bf16(vf1, pf, ot[3 + b], 0, 0, 0);
    }
  }
  asm volatile("" ::: "memory");
  #pragma unroll
  for (int b = 0; b < 3; ++b) {
    int qi = b * 16 + ql;
    #pragma unroll
    for (int r = 0; r < 4; ++r) {
      int kj = 32 + lg * 4 + r;
      *(unsigned short*)(smem + ab + qi * 80 + (kj - 32) * 2) = f2bf(st[6 + b][r] * inv[b]);
    }
    *(uint2*)(smem + ab + qi * 80 + 32 + lg * 8) = make_uint2(0u, 0u);
  }
  asm volatile("" ::: "memory");
  {
    bf16x8 vf0 = ld16(smem + ab + v_addr(ql, 64 + lg * 16));
    bf16x8 vf1 = ld16(smem + ab + v_addr(16 + ql, 64 + lg * 16));
    #pragma unroll
    for (int b = 0; b < 3; ++b) {
      bf16x8 pf = ld16(smem + ab + (b * 16 + ql) * 80 + lg * 16);
      ot[b] = __builtin_amdgcn_mfma_f32_16x16x32_bf16(vf0, pf, ot[b], 0, 0, 0);
      ot[3 + b] = __builtin_amdgcn_mfma_f32_16x16x32_bf16(vf1, pf, ot[3 + b], 0, 0, 0);
    }
  }
  // write O to s_o (aliases s_a): s_o[qi][h*32+d]
  #pragma unroll
  for (int dm = 0; dm < 2; ++dm)
    #pragma unroll
    for (int b = 0; b < 3; ++b)
      #pragma unroll
      for (int r = 0; r < 4; ++r) {
        int d = dm * 16 + lg * 4 + r;
        int qi = b * 16 + ql;
        *(unsigned short*)(smem + a_addr(qi, (h * 32 + d) * 2)) = f2bf(ot[dm * 3 + b][r]);
      }
  __syncthreads();   // attn region free, s_o complete, GEMM2 c0 staged (vmcnt drained)

  // ---- GEMM2: out = s_o @ proj_w (48x256, K=256), 4 chunks K=64, dbuf pipeline ----
  f32x4 oacc[6];
  #pragma unroll
  for (int i = 0; i < 6; ++i) oacc[i] = (f32x4){0.f, 0.f, 0.f, 0.f};

  for (int t = 0; t < 4; ++t) {
    if (t < 3) {
      int bb = ((t + 1) & 1) ? B2_A : B2_S;
      #pragma unroll
      for (int it = 0; it < 4; ++it) {
        int g = it * 512 + tid;
        int n = g >> 3, slot = g & 7;
        const char* src = (const char*)pTq + (size_t)n * 512 + (t + 1) * 128
                          + ((slot * 16) ^ ((n & 7) << 4));
        gll16(src, smem + bb + it * 8192 + wid * 1024);
      }
    }
    const int bb = (t & 1) ? B2_A : B2_S;
    #pragma unroll
    for (int ks = 0; ks < 2; ++ks) {
      bf16x8 af[3];
      #pragma unroll
      for (int mt = 0; mt < 3; ++mt)
        af[mt] = ld16(smem + a_addr(mt * 16 + ql, t * 128 + ks * 64 + lg * 16));
      #pragma unroll
      for (int nt = 0; nt < 2; ++nt) {
        int n = (2 * wid + nt) * 16 + ql;
        bf16x8 bf = ld16(smem + bb + n * 128 + ((ks * 64 + lg * 16) ^ ((n & 7) << 4)));
        #pragma unroll
        for (int mt = 0; mt < 3; ++mt)
          oacc[nt * 3 + mt] = __builtin_amdgcn_mfma_f32_16x16x32_bf16(af[mt], bf, oacc[nt * 3 + mt], 0, 0, 0);
      }
    }
    __syncthreads();
  }

  // epilogue: + proj_b, store fp32 (real tokens only)
  #pragma unroll
  for (int nt = 0; nt < 2; ++nt) {
    int ncol = (2 * wid + nt) * 16 + ql;
    float pb = proj_b[ncol];
    #pragma unroll
    for (int mt = 0; mt < 3; ++mt)
      #pragma unroll
      for (int r = 0; r < 4; ++r) {
        int token = mt * 16 + lg * 4 + r;
        if (token < 40)
          out[(size_t)w * 10240 + token * 256 + ncol] = oacc[nt * 3 + mt][r] + pb;
      }
  }
}

__global__ void octa_std(const float* __restrict__ ws, float* __restrict__ out,
                         int total_rows, size_t off)
{
  int j = blockIdx.x * 256 + threadIdx.x;
  if (j < 768) {
    float s = ws[j], ss = ws[768 + j];
    float T = (float)total_rows;
    float var = (ss - s * s / T) / (T - 1.f);
    out[off + j] = sqrtf(fmaxf(var, 0.f));
  }
}

extern "C" void kernel_launch(void* const* d_in, const int* in_sizes, int n_in,
                              void* d_out, int out_size, void* d_ws, size_t ws_size,
                              hipStream_t stream) {
  const float* data    = (const float*)d_in[0];
  const int*   rel_pos = (const int*)d_in[1];
  const float* maskp   = (const float*)d_in[2];
  const float* qkv_w   = (const float*)d_in[3];
  const float* qkv_b   = (const float*)d_in[4];
  const float* proj_w  = (const float*)d_in[5];
  const float* proj_b  = (const float*)d_in[6];
  const float* rpe_tab = (const float*)d_in[7];
  float* out = (float*)d_out;
  float* ws  = (float*)d_ws;

  const int nw = in_sizes[1] / 3072;           // 4096
  const int total_rows = nw * 40;
  const size_t std_off = (size_t)nw * 10240;

  // ws layout: [0,1536) f32 std sums; bf16 qkv_wT at +6144B (384KB); proj_wT after (128KB)
  unsigned short* wTq = (unsigned short*)((char*)d_ws + 6144);
  unsigned short* pTq = (unsigned short*)((char*)d_ws + 6144 + 393216);

  hipMemsetAsync(ws, 0, 6144, stream);
  hipLaunchKernelGGL(octa_prep, dim3(1024), dim3(256), 0, stream, qkv_w, proj_w, wTq, pTq);

  (void)hipFuncSetAttribute((const void*)octa_main,
                            hipFuncAttributeMaxDynamicSharedMemorySize, LDS_BYTES);
  hipLaunchKernelGGL(octa_main, dim3(nw), dim3(512), LDS_BYTES, stream,
                     data, rel_pos, maskp, qkv_b, proj_b, rpe_tab, wTq, pTq, ws, out);
  hipLaunchKernelGGL(octa_std, dim3(3), dim3(256), 0, stream, ws, out, total_rows, std_off);
}

// Round 5
// 416.237 us; speedup vs baseline: 10.2407x; 1.1159x over previous
//
#include <hip/hip_runtime.h>
#include <math.h>

// OctreeAttention: C=256, H=8, HD=32, K=32, G=8, W=40 (pad 48), NW=4096, RPE rows=153
#define SCALE_F 0.17677669529663687f  // 32^-0.5

typedef __bf16 bf16x8 __attribute__((ext_vector_type(8)));
typedef float f32x4 __attribute__((ext_vector_type(4)));

__device__ __forceinline__ unsigned short f2bf(float f) {
  unsigned u = __builtin_bit_cast(unsigned, f);
  u = (u + 0x7FFFu + ((u >> 16) & 1u)) >> 16;
  return (unsigned short)u;
}
__device__ __forceinline__ float bf2f(unsigned short u) {
  return __builtin_bit_cast(float, (unsigned)u << 16);
}
__device__ __forceinline__ unsigned pk2(float a, float b) {
  return (unsigned)f2bf(a) | ((unsigned)f2bf(b) << 16);
}
__device__ __forceinline__ bf16x8 ld16(const void* p) {
  int4 v = *(const int4*)p;
  return __builtin_bit_cast(bf16x8, v);
}
__device__ __forceinline__ void gll16(const void* g, void* l) {
  __builtin_amdgcn_global_load_lds(
      (const __attribute__((address_space(1))) unsigned int*)g,
      (__attribute__((address_space(3))) unsigned int*)l, 16, 0, 0);
}

// =======================================================================
// NEW PATH: 4-kernel split (needs ws_size >= 84.5 MB)
// =======================================================================

// ---- prep: weights -> bf16, transposed, PRE-SWIZZLED for frag-ready LDS ----
// layout: chunk (nh,kc) of wTq is 24576 B = [384 n][64 B], byte (n*64+cb) holds
// wT[n][kc*32 + ((cb ^ s(n))>>1)], s(n)=((n>>1)&3)<<4.  pTq: 8 chunks 16384 B.
__global__ void octa_prep2(const float* __restrict__ qkv_w, const float* __restrict__ proj_w,
                           unsigned short* __restrict__ wTq, unsigned short* __restrict__ pTq)
{
  int e = blockIdx.x * 256 + threadIdx.x;   // 262144
  if (e < 196608) {
    int nh = e / 98304, rr = e % 98304;
    int kc = rr / 12288, p2 = rr % 12288;
    int n = p2 >> 5, cw = p2 & 31;
    int kl = cw ^ (((n >> 1) & 3) << 3);
    wTq[e] = f2bf(qkv_w[(size_t)(kc * 32 + kl) * 768 + nh * 384 + n]);
  } else {
    int e2 = e - 196608;
    int kc = e2 >> 13, p2 = e2 & 8191;
    int n = p2 >> 5, cw = p2 & 31;
    int kl = cw ^ (((n >> 1) & 3) << 3);
    pTq[e2] = f2bf(proj_w[(size_t)(kc * 32 + kl) * 256 + n]);
  }
}

// ---- kernel 1: qkv GEMM (M=163840, N=384 per block-half, K=256) ----
// grid 5120 (bm = bid>>1, nh = bid&1), 512 thr. LDS 57344: A dbuf 2x4096, B dbuf 2x24576.
#define K1_A0 0
#define K1_A1 4096
#define K1_B0 8192
#define K1_B1 32768
#define K1_LDS 57344

__global__ __launch_bounds__(512, 4)
void octa_qkv(const float* __restrict__ data, const float* __restrict__ qkv_b,
              const unsigned short* __restrict__ wTq, float* __restrict__ ws,
              char* __restrict__ qg, char* __restrict__ kg, char* __restrict__ vg)
{
  extern __shared__ char smem[];
  const int tid = threadIdx.x, lane = tid & 63, wid = tid >> 6;
  const int ql = lane & 15, lg = lane >> 4;
  const int bm = blockIdx.x >> 1, nh = blockIdx.x & 1;
  const int wr = wid >> 2, wc = wid & 3;

  const int arow = tid >> 3, acq = tid & 7;
  const float* abase = data + ((size_t)bm * 64 + arow) * 256 + acq * 4;
  const int alds = arow * 64 + ((acq * 8) ^ (((arow >> 1) & 3) << 4));
  const char* wbase = (const char*)wTq + (size_t)nh * 196608;

  // prologue: A0,A1 loads; B0 staging; write A0
  float4 arr0 = *(const float4*)(abase);
  float4 arr1 = *(const float4*)(abase + 32);
  #pragma unroll
  for (int it = 0; it < 3; ++it)
    gll16(wbase + wid * 3072 + it * 1024 + lane * 16,
          smem + K1_B0 + wid * 3072 + it * 1024);
  *(uint2*)(smem + K1_A0 + alds) = make_uint2(pk2(arr0.x, arr0.y), pk2(arr0.z, arr0.w));
  __syncthreads();

  f32x4 acc[2][6];
  #pragma unroll
  for (int m = 0; m < 2; ++m)
    #pragma unroll
    for (int n = 0; n < 6; ++n) acc[m][n] = (f32x4){0.f, 0.f, 0.f, 0.f};

  #pragma unroll
  for (int t = 0; t < 8; ++t) {
    // top: issue A(t+2) reg load, B(t+1) gll16
    if (t < 6) {
      float4 tmp = *(const float4*)(abase + (t + 2) * 32);
      if ((t & 1) == 0) arr0 = tmp; else arr1 = tmp;
    }
    if (t < 7) {
      char* bb1 = smem + (((t + 1) & 1) ? K1_B1 : K1_B0);
      #pragma unroll
      for (int it = 0; it < 3; ++it)
        gll16(wbase + (size_t)(t + 1) * 24576 + wid * 3072 + it * 1024 + lane * 16,
              bb1 + wid * 3072 + it * 1024);
    }
    // compute chunk t
    const char* ab = smem + ((t & 1) ? K1_A1 : K1_A0);
    const char* bb = smem + ((t & 1) ? K1_B1 : K1_B0);
    bf16x8 af[2];
    #pragma unroll
    for (int mt = 0; mt < 2; ++mt) {
      int row = wr * 32 + mt * 16 + ql;
      af[mt] = ld16(ab + row * 64 + ((lg * 16) ^ (((row >> 1) & 3) << 4)));
    }
    #pragma unroll
    for (int nt = 0; nt < 6; ++nt) {
      int n = wc * 96 + nt * 16 + ql;
      bf16x8 bf = ld16(bb + n * 64 + ((lg * 16) ^ (((n >> 1) & 3) << 4)));
      #pragma unroll
      for (int mt = 0; mt < 2; ++mt)
        acc[mt][nt] = __builtin_amdgcn_mfma_f32_16x16x32_bf16(af[mt], bf, acc[mt][nt], 0, 0, 0);
    }
    // write A(t+1)
    if (t < 7) {
      float4 av = ((t + 1) & 1) ? arr1 : arr0;
      *(uint2*)(smem + ((t & 1) ? K1_A0 : K1_A1) + alds) =
          make_uint2(pk2(av.x, av.y), pk2(av.z, av.w));
    }
    __syncthreads();
  }

  // epilogue: bias + std partials + scatter to q/k/vT bf16 layouts
  #pragma unroll
  for (int nt = 0; nt < 6; ++nt) {
    int colg = nh * 384 + wc * 96 + nt * 16 + ql;
    int tensor = colg >> 8, h = (colg >> 5) & 7, d = colg & 31;
    float bias = qkv_b[colg];
    float s1 = 0.f, s2 = 0.f;
    #pragma unroll
    for (int mt = 0; mt < 2; ++mt) {
      float v4[4];
      #pragma unroll
      for (int r = 0; r < 4; ++r) {
        float v = acc[mt][nt][r] + bias;
        s1 += v; s2 += v * v;
        v4[r] = v;
      }
      int tg0 = bm * 64 + wr * 32 + mt * 16 + lg * 4;   // token of r=0 (4-aligned, never crosses window)
      int w = tg0 / 40, tk0 = tg0 - w * 40;
      size_t slice = (size_t)(w * 8 + h) * 2560;
      if (tensor == 0) {
        #pragma unroll
        for (int r = 0; r < 4; ++r)
          *(unsigned short*)(qg + slice + (tk0 + r) * 64 + d * 2) = f2bf(v4[r] * SCALE_F);
      } else if (tensor == 1) {
        #pragma unroll
        for (int r = 0; r < 4; ++r)
          *(unsigned short*)(kg + slice + (tk0 + r) * 64 + d * 2) = f2bf(v4[r]);
      } else {
        *(uint2*)(vg + slice + d * 80 + tk0 * 2) =
            make_uint2(pk2(v4[0], v4[1]), pk2(v4[2], v4[3]));
      }
    }
    s1 += __shfl_xor(s1, 16); s1 += __shfl_xor(s1, 32);
    s2 += __shfl_xor(s2, 16); s2 += __shfl_xor(s2, 32);
    if (lg == 0) { atomicAdd(ws + colg, s1); atomicAdd(ws + 768 + colg, s2); }
  }
}

// ---- kernel 2: attention, 1 window/block, 8 head-waves, q/k/v direct-from-global ----
#define A2_MSK 0       // mask^T bf16 [40 kj][104 B rows]
#define A2_IDX 4160    // packed idx [32 kj][128 B], XOR bit6 by kj&1
#define A2_RPT 8256    // rpeT f32 [8 h][160]
#define A2_P   13376   // per-wave P [48][80 B] x8 = 30720
#define A2_LDS 44096

__global__ __launch_bounds__(512, 4)
void octa_attn(const char* __restrict__ qg, const char* __restrict__ kg,
               const char* __restrict__ vg, const float* __restrict__ maskp,
               const int* __restrict__ rel_pos, const float* __restrict__ rpe_table,
               char* __restrict__ Og)
{
  extern __shared__ char smem[];
  const int tid = threadIdx.x, w = blockIdx.x, wid = tid >> 6;
  const int lane = tid & 63, ql = lane & 15, lg = lane >> 4, h = wid;
  const int perm = ql * 64 + lg * 16;
  const int vperm = ql * 80 + lg * 16;
  const char* qb = qg + (size_t)(w * 8 + h) * 2560;
  const char* kb = kg + (size_t)(w * 8 + h) * 2560;
  const char* vb = vg + (size_t)(w * 8 + h) * 2560;

  // issue all fragment loads up-front (latency hides under phase-0 staging)
  bf16x8 kf0 = ld16(kb + perm), kf1 = ld16(kb + 1024 + perm), kf2 = ld16(kb + 2048 + perm);
  bf16x8 qf0 = ld16(qb + perm), qf1 = ld16(qb + 1024 + perm), qf2 = ld16(qb + 2048 + perm);
  bf16x8 vA = ld16(vb + vperm);              // d 0..15,  kj 0..31
  bf16x8 vB = ld16(vb + 1280 + vperm);       // d 16..31, kj 0..31
  bf16x8 vC = ld16(vb + 64 + vperm);         // d 0..15,  kj 32..39 (lg=0 only valid)
  bf16x8 vD = ld16(vb + 1280 + 64 + vperm);  // d 16..31, kj 32..39
  if (lg != 0) {      // kj 40..63 don't exist in global: zero them (NaN-safe)
    int4 z = {0, 0, 0, 0};
    vC = __builtin_bit_cast(bf16x8, z);
    vD = __builtin_bit_cast(bf16x8, z);
  }

  // phase 0: stage mask^T, packed idx, transposed rpe
  for (int f = tid; f < 1600; f += 512) {
    float m = maskp[(size_t)w * 1600 + f];
    int qi = f / 40, kj = f - qi * 40;
    *(unsigned short*)(smem + A2_MSK + kj * 104 + qi * 2) = f2bf(m);
  }
  for (int f = tid; f < 1024; f += 512) {
    const int* rp = rel_pos + ((size_t)w * 1024 + f) * 3;
    int c0 = rp[0], c1 = rp[1], c2 = rp[2];
    c0 = min(25, max(-25, c0)); c1 = min(25, max(-25, c1)); c2 = min(25, max(-25, c2));
    unsigned pk = (unsigned)(c0 + 25) | ((unsigned)(c1 + 76) << 10) | ((unsigned)(c2 + 127) << 20);
    int qi8 = f >> 5, kj8 = f & 31;
    *(unsigned*)(smem + A2_IDX + kj8 * 128 + ((qi8 * 4) ^ ((kj8 & 1) << 6))) = pk;
  }
  for (int f = tid; f < 1224; f += 512)
    *(float*)(smem + A2_RPT + (((f & 7) * 160 + (f >> 3)) << 2)) = rpe_table[f];
  __syncthreads();

  // QK^T: ST[kj][qi] = mfma(A=k, B=q)
  f32x4 st[9];
  {
    bf16x8 kf[3] = {kf0, kf1, kf2}, qf[3] = {qf0, qf1, qf2};
    #pragma unroll
    for (int a = 0; a < 3; ++a)
      #pragma unroll
      for (int b = 0; b < 3; ++b)
        st[a * 3 + b] = __builtin_amdgcn_mfma_f32_16x16x32_bf16(
            kf[a], qf[b], (f32x4){0.f, 0.f, 0.f, 0.f}, 0, 0, 0);
  }

  // logits + mask + rpe; per-column (qi) max
  float mx[3] = {-3e38f, -3e38f, -3e38f};
  #pragma unroll
  for (int a = 0; a < 3; ++a) {
    #pragma unroll
    for (int b = 0; b < 3; ++b) {
      #pragma unroll
      for (int r = 0; r < 4; ++r) {
        int kj = a * 16 + lg * 4 + r;
        int qi = b * 16 + ql;
        float s = st[a * 3 + b][r];
        if (kj < 40) {
          if (qi < 40) {
            s += bf2f(*(const unsigned short*)(smem + A2_MSK + kj * 104 + qi * 2));
            if (kj >= 8 && qi >= 8) {
              unsigned pk = *(const unsigned*)(smem + A2_IDX + (kj - 8) * 128 +
                                               (((qi - 8) * 4) ^ (((kj - 8) & 1) << 6)));
              s += *(const float*)(smem + A2_RPT + ((h * 160 + (pk & 1023)) << 2))
                 + *(const float*)(smem + A2_RPT + ((h * 160 + ((pk >> 10) & 1023)) << 2))
                 + *(const float*)(smem + A2_RPT + ((h * 160 + (pk >> 20)) << 2));
            }
          }
        } else {
          s = -1e30f;
        }
        st[a * 3 + b][r] = s;
        mx[b] = fmaxf(mx[b], s);
      }
    }
  }
  #pragma unroll
  for (int b = 0; b < 3; ++b) {
    mx[b] = fmaxf(mx[b], __shfl_xor(mx[b], 16));
    mx[b] = fmaxf(mx[b], __shfl_xor(mx[b], 32));
  }
  float sum[3] = {0.f, 0.f, 0.f};
  #pragma unroll
  for (int a = 0; a < 3; ++a)
    #pragma unroll
    for (int b = 0; b < 3; ++b)
      #pragma unroll
      for (int r = 0; r < 4; ++r) {
        float e = __expf(st[a * 3 + b][r] - mx[b]);
        st[a * 3 + b][r] = e;
        sum[b] += e;
      }
  float inv[3];
  #pragma unroll
  for (int b = 0; b < 3; ++b) {
    sum[b] += __shfl_xor(sum[b], 16);
    sum[b] += __shfl_xor(sum[b], 32);
    inv[b] = 1.f / sum[b];
  }

  // PV in two kj-halves; per-wave P buffer
  char* pb_ = smem + A2_P + wid * 3840;
  f32x4 ot[6];
  #pragma unroll
  for (int i = 0; i < 6; ++i) ot[i] = (f32x4){0.f, 0.f, 0.f, 0.f};

  #pragma unroll
  for (int a = 0; a < 2; ++a)
    #pragma unroll
    for (int b = 0; b < 3; ++b)
      #pragma unroll
      for (int r = 0; r < 4; ++r) {
        int kj = a * 16 + lg * 4 + r, qi = b * 16 + ql;
        *(unsigned short*)(pb_ + qi * 80 + kj * 2) = f2bf(st[a * 3 + b][r] * inv[b]);
      }
  asm volatile("" ::: "memory");
  #pragma unroll
  for (int b = 0; b < 3; ++b) {
    bf16x8 pf = ld16(pb_ + (b * 16 + ql) * 80 + lg * 16);
    ot[b]     = __builtin_amdgcn_mfma_f32_16x16x32_bf16(vA, pf, ot[b], 0, 0, 0);
    ot[3 + b] = __builtin_amdgcn_mfma_f32_16x16x32_bf16(vB, pf, ot[3 + b], 0, 0, 0);
  }
  asm volatile("" ::: "memory");
  #pragma unroll
  for (int b = 0; b < 3; ++b) {
    int qi = b * 16 + ql;
    #pragma unroll
    for (int r = 0; r < 4; ++r)
      *(unsigned short*)(pb_ + qi * 80 + (lg * 4 + r) * 2) = f2bf(st[6 + b][r] * inv[b]);
    *(uint2*)(pb_ + qi * 80 + 32 + lg * 8) = make_uint2(0u, 0u);
  }
  asm volatile("" ::: "memory");
  #pragma unroll
  for (int b = 0; b < 3; ++b) {
    bf16x8 pf = ld16(pb_ + (b * 16 + ql) * 80 + lg * 16);
    ot[b]     = __builtin_amdgcn_mfma_f32_16x16x32_bf16(vC, pf, ot[b], 0, 0, 0);
    ot[3 + b] = __builtin_amdgcn_mfma_f32_16x16x32_bf16(vD, pf, ot[3 + b], 0, 0, 0);
  }

  // O store (Og aliases kg: wait for ALL waves' k reads to be consumed)
  __syncthreads();
  #pragma unroll
  for (int dm = 0; dm < 2; ++dm)
    #pragma unroll
    for (int b = 0; b < 3; ++b) {
      int qi = b * 16 + ql;
      if (b == 2 && ql >= 8) continue;   // tokens >= 40 don't exist
      unsigned u0 = pk2(ot[dm * 3 + b][0], ot[dm * 3 + b][1]);
      unsigned u1 = pk2(ot[dm * 3 + b][2], ot[dm * 3 + b][3]);
      int tg = w * 40 + qi;
      int colb = (h * 32 + dm * 16 + lg * 4) * 2;
      *(uint2*)(Og + (size_t)tg * 512 + (colb ^ (((tg >> 1) & 3) << 4))) = make_uint2(u0, u1);
    }
}

// ---- kernel 3: proj GEMM (M=163840, N=256, K=256), all-gll16 dbuf ----
#define P3_A0 0
#define P3_A1 8192
#define P3_B0 16384
#define P3_B1 32768
#define P3_LDS 49152

__global__ __launch_bounds__(512, 4)
void octa_proj(const char* __restrict__ Og, const unsigned short* __restrict__ pTq,
               const float* __restrict__ proj_b, float* __restrict__ out)
{
  extern __shared__ char smem[];
  const int tid = threadIdx.x, lane = tid & 63, wid = tid >> 6;
  const int ql = lane & 15, lg = lane >> 4;
  const int bm = blockIdx.x;
  const int wr = wid >> 2, wc = wid & 3;
  const char* pbase = (const char*)pTq;

  // prologue: stage A0 (1 slot/thread) + B0 (2/thread)
  gll16(Og + ((size_t)bm * 128 + (tid >> 2)) * 512 + (tid & 3) * 16,
        smem + P3_A0 + wid * 1024);
  #pragma unroll
  for (int it = 0; it < 2; ++it)
    gll16(pbase + (wid * 128 + it * 64 + lane) * 16, smem + P3_B0 + wid * 2048 + it * 1024);
  __syncthreads();

  f32x4 acc[4][4];
  #pragma unroll
  for (int m = 0; m < 4; ++m)
    #pragma unroll
    for (int n = 0; n < 4; ++n) acc[m][n] = (f32x4){0.f, 0.f, 0.f, 0.f};

  #pragma unroll
  for (int t = 0; t < 8; ++t) {
    if (t < 7) {
      char* ab1 = smem + (((t + 1) & 1) ? P3_A1 : P3_A0);
      char* bb1 = smem + (((t + 1) & 1) ? P3_B1 : P3_B0);
      gll16(Og + ((size_t)bm * 128 + (tid >> 2)) * 512 + (t + 1) * 64 + (tid & 3) * 16,
            ab1 + wid * 1024);
      #pragma unroll
      for (int it = 0; it < 2; ++it)
        gll16(pbase + (size_t)(t + 1) * 16384 + (wid * 128 + it * 64 + lane) * 16,
              bb1 + wid * 2048 + it * 1024);
    }
    const char* ab = smem + ((t & 1) ? P3_A1 : P3_A0);
    const char* bb = smem + ((t & 1) ? P3_B1 : P3_B0);
    bf16x8 af[4];
    #pragma unroll
    for (int mt = 0; mt < 4; ++mt) {
      int row = wr * 64 + mt * 16 + ql;
      af[mt] = ld16(ab + row * 64 + ((lg * 16) ^ (((row >> 1) & 3) << 4)));
    }
    #pragma unroll
    for (int nt = 0; nt < 4; ++nt) {
      int n = wc * 64 + nt * 16 + ql;
      bf16x8 bf = ld16(bb + n * 64 + ((lg * 16) ^ (((n >> 1) & 3) << 4)));
      #pragma unroll
      for (int mt = 0; mt < 4; ++mt)
        acc[mt][nt] = __builtin_amdgcn_mfma_f32_16x16x32_bf16(af[mt], bf, acc[mt][nt], 0, 0, 0);
    }
    __syncthreads();
  }

  #pragma unroll
  for (int nt = 0; nt < 4; ++nt) {
    int col = wc * 64 + nt * 16 + ql;
    float pb = proj_b[col];
    #pragma unroll
    for (int mt = 0; mt < 4; ++mt)
      #pragma unroll
      for (int r = 0; r < 4; ++r) {
        int tg = bm * 128 + wr * 64 + mt * 16 + lg * 4 + r;
        out[(size_t)tg * 256 + col] = acc[mt][nt][r] + pb;
      }
  }
}

// ---- std finalize (shared by both paths) ----
__global__ void octa_std(const float* __restrict__ ws, float* __restrict__ out,
                         int total_rows, size_t off)
{
  int j = blockIdx.x * 256 + threadIdx.x;
  if (j < 768) {
    float s = ws[j], ss = ws[768 + j];
    float T = (float)total_rows;
    float var = (ss - s * s / T) / (T - 1.f);
    out[off + j] = sqrtf(fmaxf(var, 0.f));
  }
}

// =======================================================================
// FALLBACK PATH: round-4 fused kernel (verified), used if ws too small
// =======================================================================
#define O_RPE 0
#define O_MSK 4896
#define O_IDX 8096
#define O_A   12192
#define O_ATT 36768
#define B1_SZ 49152
#define ATT_STRIDE 11776
#define AK 3840
#define AV 7680
#define B2_S (O_ATT + 94208)
#define B2_A O_ATT
#define LDS_BYTES_V4 163744

__device__ __forceinline__ int a_addr(int row, int byte) {
  return O_A + row * 512 + (byte ^ ((row & 7) << 4));
}
__device__ __forceinline__ int v_addr(int d, int byte) {
  return AV + d * 128 + (byte ^ ((d & 7) << 4));
}

__global__ void octa_prep_v4(const float* __restrict__ qkv_w, const float* __restrict__ proj_w,
                             unsigned short* __restrict__ wTq, unsigned short* __restrict__ pTq)
{
  int idx = blockIdx.x * 256 + threadIdx.x;
  if (idx < 196608) {
    int n = idx >> 8, k = idx & 255;
    wTq[idx] = f2bf(qkv_w[k * 768 + n]);
  } else {
    int i = idx - 196608;
    int n = i >> 8, k = i & 255;
    pTq[i] = f2bf(proj_w[k * 256 + n]);
  }
}

__global__ __launch_bounds__(512, 2)
void octa_main_v4(const float* __restrict__ data, const int* __restrict__ rel_pos,
                  const float* __restrict__ maskp, const float* __restrict__ qkv_b,
                  const float* __restrict__ proj_b, const float* __restrict__ rpe_table,
                  const unsigned short* __restrict__ wTq, const unsigned short* __restrict__ pTq,
                  float* __restrict__ ws, float* __restrict__ out)
{
  extern __shared__ char smem[];
  float* s_rpe = (float*)(smem + O_RPE);
  const int tid = threadIdx.x;
  const int w   = blockIdx.x;
  const int wid = tid >> 6;
  const int lane = tid & 63;
  const int ql = lane & 15;
  const int lg = lane >> 4;
  const int h  = wid;
  const int ab = O_ATT + wid * ATT_STRIDE;

  {
    #pragma unroll
    for (int it = 0; it < 6; ++it) {
      int g = it * 512 + tid;
      int n = g >> 2, slot = g & 3;
      const char* src = (const char*)wTq + (size_t)n * 512 + ((slot * 16) ^ ((n & 3) << 4));
      gll16(src, smem + O_ATT + it * 8192 + wid * 1024);
    }
  }
  for (int f = tid; f < 1224; f += 512) s_rpe[f] = rpe_table[f];
  for (int f = tid; f < 400; f += 512) {
    float4 m4 = ((const float4*)(maskp + (size_t)w * 1600))[f];
    uint2 pk;
    pk.x = pk2(m4.x, m4.y); pk.y = pk2(m4.z, m4.w);
    *(uint2*)(smem + O_MSK + f * 8) = pk;
  }
  for (int p = tid; p < 1024; p += 512) {
    const int* rp = rel_pos + ((size_t)w * 1024 + p) * 3;
    int c0 = rp[0], c1 = rp[1], c2 = rp[2];
    c0 = min(25, max(-25, c0)); c1 = min(25, max(-25, c1)); c2 = min(25, max(-25, c2));
    unsigned pk = (unsigned)(c0 + 25) | ((unsigned)(c1 + 76) << 10) | ((unsigned)(c2 + 127) << 20);
    *(unsigned*)(smem + O_IDX + ((p * 4) ^ (((p >> 5) & 7) << 4))) = pk;
  }
  {
    const float4* src = (const float4*)(data + (size_t)w * 10240);
    for (int f = tid; f < 2560; f += 512) {
      int token = f >> 6, q4 = f & 63;
      float4 d4 = src[f];
      uint2 pk;
      pk.x = pk2(d4.x, d4.y); pk.y = pk2(d4.z, d4.w);
      *(uint2*)(smem + a_addr(token, q4 * 8)) = pk;
    }
    int token = 40 + (tid >> 6), byte = (tid & 63) * 8;
    *(uint2*)(smem + a_addr(token, byte)) = make_uint2(0u, 0u);
  }
  __syncthreads();

  f32x4 acc[18];
  #pragma unroll
  for (int i = 0; i < 18; ++i) acc[i] = (f32x4){0.f, 0.f, 0.f, 0.f};

  for (int t = 0; t < 8; ++t) {
    if (t < 7) {
      int bb = O_ATT + ((t + 1) & 1) * B1_SZ;
      #pragma unroll
      for (int it = 0; it < 6; ++it) {
        int g = it * 512 + tid;
        int n = g >> 2, slot = g & 3;
        const char* src = (const char*)wTq + (size_t)n * 512 + (t + 1) * 64
                          + ((slot * 16) ^ ((n & 3) << 4));
        gll16(src, smem + bb + it * 8192 + wid * 1024);
      }
    }
    const int bb = O_ATT + (t & 1) * B1_SZ;
    bf16x8 af[3];
    #pragma unroll
    for (int mt = 0; mt < 3; ++mt)
      af[mt] = ld16(smem + a_addr(mt * 16 + ql, t * 64 + lg * 16));
    #pragma unroll
    for (int j = 0; j < 6; ++j) {
      int n = ((j >> 1) * 16 + 2 * wid + (j & 1)) * 16 + ql;
      bf16x8 bf = ld16(smem + bb + n * 64 + ((lg * 16) ^ ((n & 3) << 4)));
      #pragma unroll
      for (int mt = 0; mt < 3; ++mt)
        acc[j * 3 + mt] = __builtin_amdgcn_mfma_f32_16x16x32_bf16(af[mt], bf, acc[j * 3 + mt], 0, 0, 0);
    }
    __syncthreads();
  }

  {
    #pragma unroll
    for (int it = 0; it < 4; ++it) {
      int g = it * 512 + tid;
      int n = g >> 3, slot = g & 7;
      const char* src = (const char*)pTq + (size_t)n * 512 + ((slot * 16) ^ ((n & 7) << 4));
      gll16(src, smem + B2_S + it * 8192 + wid * 1024);
    }
  }

  #pragma unroll
  for (int j = 0; j < 6; ++j) {
    int sec = j >> 1;
    int ncol = sec * 256 + 32 * wid + (j & 1) * 16 + ql;
    int d = (j & 1) * 16 + ql;
    float bias = qkv_b[ncol];
    float s1 = 0.f, s2 = 0.f;
    #pragma unroll
    for (int mt = 0; mt < 3; ++mt) {
      #pragma unroll
      for (int r = 0; r < 4; ++r) {
        int token = mt * 16 + lg * 4 + r;
        float v = acc[j * 3 + mt][r] + bias;
        if (token < 40) { s1 += v; s2 += v * v; }
        if (sec == 0)
          *(unsigned short*)(smem + ab + token * 80 + d * 2) = f2bf(v * SCALE_F);
        else if (sec == 1)
          *(unsigned short*)(smem + ab + AK + token * 80 + d * 2) = f2bf(v);
        else
          *(unsigned short*)(smem + ab + v_addr(d, token * 2)) = f2bf(v);
      }
    }
    s1 += __shfl_xor(s1, 16); s1 += __shfl_xor(s1, 32);
    s2 += __shfl_xor(s2, 16); s2 += __shfl_xor(s2, 32);
    if (lg == 0) { atomicAdd(ws + ncol, s1); atomicAdd(ws + 768 + ncol, s2); }
  }
  {
    int zd = lane >> 1;
    int zb = 96 + (lane & 1) * 16;
    *(int4*)(smem + ab + v_addr(zd, zb)) = (int4){0, 0, 0, 0};
  }
  asm volatile("" ::: "memory");

  f32x4 st[9];
  {
    bf16x8 kf[3], qf[3];
    #pragma unroll
    for (int a = 0; a < 3; ++a) kf[a] = ld16(smem + ab + AK + (a * 16 + ql) * 80 + lg * 16);
    #pragma unroll
    for (int b = 0; b < 3; ++b) qf[b] = ld16(smem + ab + (b * 16 + ql) * 80 + lg * 16);
    #pragma unroll
    for (int a = 0; a < 3; ++a)
      #pragma unroll
      for (int b = 0; b < 3; ++b)
        st[a * 3 + b] = __builtin_amdgcn_mfma_f32_16x16x32_bf16(
            kf[a], qf[b], (f32x4){0.f, 0.f, 0.f, 0.f}, 0, 0, 0);
  }

  float mx[3] = {-3e38f, -3e38f, -3e38f};
  #pragma unroll
  for (int a = 0; a < 3; ++a) {
    #pragma unroll
    for (int b = 0; b < 3; ++b) {
      #pragma unroll
      for (int r = 0; r < 4; ++r) {
        int kj = a * 16 + lg * 4 + r;
        int qi = b * 16 + ql;
        float s = st[a * 3 + b][r];
        if (kj < 40) {
          if (qi < 40) {
            s += bf2f(*(const unsigned short*)(smem + O_MSK + (qi * 40 + kj) * 2));
            if (kj >= 8 && qi >= 8) {
              int p = (qi - 8) * 32 + (kj - 8);
              unsigned pk = *(const unsigned*)(smem + O_IDX + ((p * 4) ^ (((p >> 5) & 7) << 4)));
              s += s_rpe[(pk & 1023) * 8 + h] + s_rpe[((pk >> 10) & 1023) * 8 + h]
                 + s_rpe[(pk >> 20) * 8 + h];
            }
          }
        } else {
          s = -1e30f;
        }
        st[a * 3 + b][r] = s;
        mx[b] = fmaxf(mx[b], s);
      }
    }
  }
  #pragma unroll
  for (int b = 0; b < 3; ++b) {
    mx[b] = fmaxf(mx[b], __shfl_xor(mx[b], 16));
    mx[b] = fmaxf(mx[b], __shfl_xor(mx[b], 32));
  }
  float sum[3] = {0.f, 0.f, 0.f};
  #pragma unroll
  for (int a = 0; a < 3; ++a)
    #pragma unroll
    for (int b = 0; b < 3; ++b)
      #pragma unroll
      for (int r = 0; r < 4; ++r) {
        float e = __expf(st[a * 3 + b][r] - mx[b]);
        st[a * 3 + b][r] = e;
        sum[b] += e;
      }
  float inv[3];
  #pragma unroll
  for (int b = 0; b < 3; ++b) {
    sum[b] += __shfl_xor(sum[b], 16);
    sum[b] += __shfl_xor(sum[b], 32);
    inv[b] = 1.f / sum[b];
  }

  f32x4 ot[6];
  #pragma unroll
  for (int i = 0; i < 6; ++i) ot[i] = (f32x4){0.f, 0.f, 0.f, 0.f};

  #pragma unroll
  for (int a = 0; a < 2; ++a)
    #pragma unroll
    for (int b = 0; b < 3; ++b)
      #pragma unroll
      for (int r = 0; r < 4; ++r) {
        int kj = a * 16 + lg * 4 + r, qi = b * 16 + ql;
        *(unsigned short*)(smem + ab + qi * 80 + kj * 2) = f2bf(st[a * 3 + b][r] * inv[b]);
      }
  asm volatile("" ::: "memory");
  {
    bf16x8 vf0 = ld16(smem + ab + v_addr(ql, lg * 16));
    bf16x8 vf1 = ld16(smem + ab + v_addr(16 + ql, lg * 16));
    #pragma unroll
    for (int b = 0; b < 3; ++b) {
      bf16x8 pf = ld16(smem + ab + (b * 16 + ql) * 80 + lg * 16);
      ot[b] = __builtin_amdgcn_mfma_f32_16x16x32_bf16(vf0, pf, ot[b], 0, 0, 0);
      ot[3 + b] = __builtin_amdgcn_mfma_f32_16x16x32_bf16(vf1, pf, ot[3 + b], 0, 0, 0);
    }
  }
  asm volatile("" ::: "memory");
  #pragma unroll
  for (int b = 0; b < 3; ++b) {
    int qi = b * 16 + ql;
    #pragma unroll
    for (int r = 0; r < 4; ++r) {
      int kj = 32 + lg * 4 + r;
      *(unsigned short*)(smem + ab + qi * 80 + (kj - 32) * 2) = f2bf(st[6 + b][r] * inv[b]);
    }
    *(uint2*)(smem + ab + qi * 80 + 32 + lg * 8) = make_uint2(0u, 0u);
  }
  asm volatile("" ::: "memory");
  {
    bf16x8 vf0 = ld16(smem + ab + v_addr(ql, 64 + lg * 16));
    bf16x8 vf1 = ld16(smem + ab + v_addr(16 + ql, 64 + lg * 16));
    #pragma unroll
    for (int b = 0; b < 3; ++b) {
      bf16x8 pf = ld16(smem + ab + (b * 16 + ql) * 80 + lg * 16);
      ot[b] = __builtin_amdgcn_mfma_f32_16x16x32_bf16(vf0, pf, ot[b], 0, 0, 0);
      ot[3 + b] = __builtin_amdgcn_mfma_f32_16x16x32_bf16(vf1, pf, ot[3 + b], 0, 0, 0);
    }
  }
  #pragma unroll
  for (int dm = 0; dm < 2; ++dm)
    #pragma unroll
    for (int b = 0; b < 3; ++b)
      #pragma unroll
      for (int r = 0; r < 4; ++r) {
        int d = dm * 16 + lg * 4 + r;
        int qi = b * 16 + ql;
        *(unsigned short*)(smem + a_addr(qi, (h * 32 + d) * 2)) = f2bf(ot[dm * 3 + b][r]);
      }
  __syncthreads();

  f32x4 oacc[6];
  #pragma unroll
  for (int i = 0; i < 6; ++i) oacc[i] = (f32x4){0.f, 0.f, 0.f, 0.f};

  for (int t = 0; t < 4; ++t) {
    if (t < 3) {
      int bb = ((t + 1) & 1) ? B2_A : B2_S;
      #pragma unroll
      for (int it = 0; it < 4; ++it) {
        int g = it * 512 + tid;
        int n = g >> 3, slot = g & 7;
        const char* src = (const char*)pTq + (size_t)n * 512 + (t + 1) * 128
                          + ((slot * 16) ^ ((n & 7) << 4));
        gll16(src, smem + bb + it * 8192 + wid * 1024);
      }
    }
    const int bb = (t & 1) ? B2_A : B2_S;
    #pragma unroll
    for (int ks = 0; ks < 2; ++ks) {
      bf16x8 af[3];
      #pragma unroll
      for (int mt = 0; mt < 3; ++mt)
        af[mt] = ld16(smem + a_addr(mt * 16 + ql, t * 128 + ks * 64 + lg * 16));
      #pragma unroll
      for (int nt = 0; nt < 2; ++nt) {
        int n = (2 * wid + nt) * 16 + ql;
        bf16x8 bf = ld16(smem + bb + n * 128 + ((ks * 64 + lg * 16) ^ ((n & 7) << 4)));
        #pragma unroll
        for (int mt = 0; mt < 3; ++mt)
          oacc[nt * 3 + mt] = __builtin_amdgcn_mfma_f32_16x16x32_bf16(af[mt], bf, oacc[nt * 3 + mt], 0, 0, 0);
      }
    }
    __syncthreads();
  }

  #pragma unroll
  for (int nt = 0; nt < 2; ++nt) {
    int ncol = (2 * wid + nt) * 16 + ql;
    float pb = proj_b[ncol];
    #pragma unroll
    for (int mt = 0; mt < 3; ++mt)
      #pragma unroll
      for (int r = 0; r < 4; ++r) {
        int token = mt * 16 + lg * 4 + r;
        if (token < 40)
          out[(size_t)w * 10240 + token * 256 + ncol] = oacc[nt * 3 + mt][r] + pb;
      }
  }
}

// =======================================================================
extern "C" void kernel_launch(void* const* d_in, const int* in_sizes, int n_in,
                              void* d_out, int out_size, void* d_ws, size_t ws_size,
                              hipStream_t stream) {
  const float* data    = (const float*)d_in[0];
  const int*   rel_pos = (const int*)d_in[1];
  const float* maskp   = (const float*)d_in[2];
  const float* qkv_w   = (const float*)d_in[3];
  const float* qkv_b   = (const float*)d_in[4];
  const float* proj_w  = (const float*)d_in[5];
  const float* proj_b  = (const float*)d_in[6];
  const float* rpe_tab = (const float*)d_in[7];
  float* out = (float*)d_out;
  float* ws  = (float*)d_ws;

  const int nw = in_sizes[1] / 3072;           // 4096
  const int total_rows = nw * 40;
  const size_t std_off = (size_t)nw * 10240;

  // ws layout (new path): [0,6144) sums | wTq 393216 | pTq 131072 | k/O 83886080
  const size_t WS_NEED = 530432ull + 83886080ull;

  unsigned short* wTq = (unsigned short*)((char*)d_ws + 6144);
  unsigned short* pTq = (unsigned short*)((char*)d_ws + 399360);

  hipMemsetAsync(ws, 0, 6144, stream);

  if (ws_size >= WS_NEED) {
    char* kg = (char*)d_ws + 530432;
    char* Og = kg;                               // O overwrites k (dead after attn reads)
    char* qg = (char*)d_out;                     // q in d_out[0, 83886080)
    char* vg = (char*)d_out + 83886080;          // vT in d_out[83886080, 167772160)

    hipLaunchKernelGGL(octa_prep2, dim3(1024), dim3(256), 0, stream, qkv_w, proj_w, wTq, pTq);
    hipLaunchKernelGGL(octa_qkv, dim3(nw * 40 / 64 * 2), dim3(512), K1_LDS, stream,
                       data, qkv_b, wTq, ws, qg, kg, vg);
    hipLaunchKernelGGL(octa_attn, dim3(nw), dim3(512), A2_LDS, stream,
                       qg, kg, vg, maskp, rel_pos, rpe_tab, Og);
    hipLaunchKernelGGL(octa_proj, dim3(nw * 40 / 128), dim3(512), P3_LDS, stream,
                       Og, pTq, proj_b, out);
    hipLaunchKernelGGL(octa_std, dim3(3), dim3(256), 0, stream, ws, out, total_rows, std_off);
  } else {
    hipLaunchKernelGGL(octa_prep_v4, dim3(1024), dim3(256), 0, stream, qkv_w, proj_w, wTq, pTq);
    (void)hipFuncSetAttribute((const void*)octa_main_v4,
                              hipFuncAttributeMaxDynamicSharedMemorySize, LDS_BYTES_V4);
    hipLaunchKernelGGL(octa_main_v4, dim3(nw), dim3(512), LDS_BYTES_V4, stream,
                       data, rel_pos, maskp, qkv_b, proj_b, rpe_tab, wTq, pTq, ws, out);
    hipLaunchKernelGGL(octa_std, dim3(3), dim3(256), 0, stream, ws, out, total_rows, std_off);
  }
}